// Round 11
// baseline (125.230 us; speedup 1.0000x reference)
//
#include <hip/hip_runtime.h>

// GCN on a directed chain i->i+1 with self-loops.
//
// Math (symmetric normalization on chain + self-loops):
//   deg[0]=1, deg[j>=1]=2  ->  dis[0]=1, dis[j>=1]=1/sqrt(2)
//   stencil(h)[j] = a_j*h[j] + c_j*h[j-1],  a_0=1, a_j=0.5 (j>=1)
//   c_0=0 (and c_j=0 for j<0), c_1=1/sqrt(2), c_j=0.5 (j>=2)
//   out = g @ W3 + b3   where  g = stencil(relu(stencil(relu(stencil(x@W1)
//         +b1)@W2)+b2))  (stencil commutes with right-matmul by linearity).
//
// Evidence ledger for K2 (268 MB store stream, fill-demonstrated 7.0 TB/s):
//   R7  blocks 2048->512:            69.4us  (-24% BW; needs >=8 blocks/CU)
//   R8  nontemporal stores:          64.6us  (L2 write-back HELPS; reverted)
//   R9  4-row store bursting:        55.1us  (neutral; reverted)
//   R10 float2 width + 2x occupancy: 56.6us  (neutral; dependency-latency
//                                             theory falsified; reverted)
// R10 -> R11 (single variable vs R6-best 54.4us): block->address mapping.
// Replicate the fill kernel's grid-stride sweep exactly: 1-D grid, linear
// float4 index, grid span = 2^21 floats = 256 full rows, so each thread's
// column set is iteration-invariant (W3 register slab preserved) while the
// whole grid writes one contiguous 8MB window per iteration, sweeping
// monotonically (vs R6's 256 scattered 32KB rows at 1MB stride).

#define N_NODES 8192
#define F_IN 4
#define H1 32
#define H2 16

#define FRONT_ROWS 128        // g-rows per front block

__device__ __forceinline__ float coefA(int j) { return j == 0 ? 1.0f : 0.5f; }
__device__ __forceinline__ float coefC(int j) {
    return j <= 0 ? 0.0f : (j == 1 ? 0.70710678118654752f : 0.5f);
}

// ---------------- K1: x -> g = stencil(h2), [N,16] ----------------
__global__ void __launch_bounds__(256) gnn_front(
    const float* __restrict__ x,  const float* __restrict__ W1,
    const float* __restrict__ b1, const float* __restrict__ W2,
    const float* __restrict__ b2, float* __restrict__ g)
{
    __shared__ float sW1t[H1 * F_IN];            // transposed: [k][f]
    __shared__ float sb1[H1];
    __shared__ float sW2[H1 * H2];               // [k][m]
    __shared__ float sb2[H2];
    __shared__ float st2[FRONT_ROWS + 2][H2];    // 8320 B

    const int t = threadIdx.x;
    const int row0 = blockIdx.x * FRONT_ROWS;

    if (t < H1 * F_IN) sW1t[t] = W1[(t & 3) * H1 + (t >> 2)];  // sW1t[k*4+f]=W1[f][k]
    if (t < H1) sb1[t] = b1[t];
    if (t < H2) sb2[t] = b2[t];
    sW2[t] = W2[t];
    sW2[t + 256] = W2[t + 256];
    __syncthreads();

    // t2 rows for nodes row0-2 .. row0+FRONT_ROWS-1, lanes 0..FRONT_ROWS+1
    if (t < FRONT_ROWS + 2) {
        const int jj = row0 - 2 + t;
        float acc[H2];
        #pragma unroll
        for (int m = 0; m < H2; ++m) acc[m] = 0.f;
        if (jj >= 0) {
            const float4 xc = *reinterpret_cast<const float4*>(&x[jj * F_IN]);
            float4 xp = make_float4(0.f, 0.f, 0.f, 0.f);
            if (jj >= 1) xp = *reinterpret_cast<const float4*>(&x[(jj - 1) * F_IN]);
            const float a = coefA(jj), c = coefC(jj);
            #pragma unroll
            for (int k = 0; k < H1; ++k) {
                const float4 wk = *reinterpret_cast<const float4*>(&sW1t[k * 4]);
                const float t1c = xc.x * wk.x + xc.y * wk.y + xc.z * wk.z + xc.w * wk.w;
                const float t1p = xp.x * wk.x + xp.y * wk.y + xp.z * wk.z + xp.w * wk.w;
                float h = a * t1c + c * t1p + sb1[k];
                h = h > 0.f ? h : 0.f;
                #pragma unroll
                for (int m = 0; m < H2; ++m) acc[m] += h * sW2[k * H2 + m];
            }
        }
        #pragma unroll
        for (int m = 0; m < H2; ++m) st2[t][m] = acc[m];
    }
    __syncthreads();

    // g rows for nodes row0 .. row0+FRONT_ROWS-1, lanes 0..FRONT_ROWS-1
    if (t < FRONT_ROWS) {
        const int j = row0 + t;   // st2[t+2]=t2[j], st2[t+1]=t2[j-1], st2[t]=t2[j-2]
        const float aj = coefA(j),     cj = coefC(j);
        const float ap = coefA(j - 1), cp = coefC(j - 1);
        float gout[H2];
        #pragma unroll
        for (int m = 0; m < H2; ++m) {
            const float bm = sb2[m];
            float h2c = aj * st2[t + 2][m] + cj * st2[t + 1][m] + bm;
            h2c = h2c > 0.f ? h2c : 0.f;
            float h2p = ap * st2[t + 1][m] + cp * st2[t][m] + bm;
            h2p = h2p > 0.f ? h2p : 0.f;
            gout[m] = aj * h2c + cj * h2p;       // g[j] = stencil(h2)[j]
        }
        #pragma unroll
        for (int m = 0; m < H2; m += 4) {
            *reinterpret_cast<float4*>(&g[j * H2 + m]) =
                make_float4(gout[m], gout[m + 1], gout[m + 2], gout[m + 3]);
        }
    }
}

// ------- K2: out = g @ W3 + b3, [N, N] — fill-pattern grid-stride streamer -------
// Linear float4 index; grid span = 2048 blocks * 256 thr * 4 = 2^21 floats
// = exactly 256 rows -> col set per thread is iteration-invariant, rows
// advance by 256 per iteration (whole grid sweeps contiguous 8MB windows).
__global__ void __launch_bounds__(256) gnn_out(
    const float* __restrict__ g, const float* __restrict__ W3,
    const float* __restrict__ b3, float* __restrict__ out)
{
    const int gtid  = blockIdx.x * 256 + threadIdx.x;   // 0..524287
    const int col0  = (gtid * 4) & (N_NODES - 1);
    const int rbase = (gtid * 4) >> 13;                 // 0..255

    // W3 column slab in registers: 16 x float4 = 64 VGPRs, loaded once
    float4 w[H2];
    #pragma unroll
    for (int k = 0; k < H2; ++k)
        w[k] = *reinterpret_cast<const float4*>(&W3[k * N_NODES + col0]);
    const float4 bb = *reinterpret_cast<const float4*>(&b3[col0]);

    #pragma unroll 4
    for (int i = 0; i < N_NODES / 256; ++i) {           // 32 iterations
        const int row = rbase + i * 256;
        const float* gr = g + row * H2;
        // wave-uniform addresses -> scalar-cache broadcast loads
        const float4 g0 = *reinterpret_cast<const float4*>(&gr[0]);
        const float4 g1 = *reinterpret_cast<const float4*>(&gr[4]);
        const float4 g2 = *reinterpret_cast<const float4*>(&gr[8]);
        const float4 g3 = *reinterpret_cast<const float4*>(&gr[12]);
        float4 acc = bb;
        acc.x += g0.x*w[0].x;  acc.y += g0.x*w[0].y;  acc.z += g0.x*w[0].z;  acc.w += g0.x*w[0].w;
        acc.x += g0.y*w[1].x;  acc.y += g0.y*w[1].y;  acc.z += g0.y*w[1].z;  acc.w += g0.y*w[1].w;
        acc.x += g0.z*w[2].x;  acc.y += g0.z*w[2].y;  acc.z += g0.z*w[2].z;  acc.w += g0.z*w[2].w;
        acc.x += g0.w*w[3].x;  acc.y += g0.w*w[3].y;  acc.z += g0.w*w[3].z;  acc.w += g0.w*w[3].w;
        acc.x += g1.x*w[4].x;  acc.y += g1.x*w[4].y;  acc.z += g1.x*w[4].z;  acc.w += g1.x*w[4].w;
        acc.x += g1.y*w[5].x;  acc.y += g1.y*w[5].y;  acc.z += g1.y*w[5].z;  acc.w += g1.y*w[5].w;
        acc.x += g1.z*w[6].x;  acc.y += g1.z*w[6].y;  acc.z += g1.z*w[6].z;  acc.w += g1.z*w[6].w;
        acc.x += g1.w*w[7].x;  acc.y += g1.w*w[7].y;  acc.z += g1.w*w[7].z;  acc.w += g1.w*w[7].w;
        acc.x += g2.x*w[8].x;  acc.y += g2.x*w[8].y;  acc.z += g2.x*w[8].z;  acc.w += g2.x*w[8].w;
        acc.x += g2.y*w[9].x;  acc.y += g2.y*w[9].y;  acc.z += g2.y*w[9].z;  acc.w += g2.y*w[9].w;
        acc.x += g2.z*w[10].x; acc.y += g2.z*w[10].y; acc.z += g2.z*w[10].z; acc.w += g2.z*w[10].w;
        acc.x += g2.w*w[11].x; acc.y += g2.w*w[11].y; acc.z += g2.w*w[11].z; acc.w += g2.w*w[11].w;
        acc.x += g3.x*w[12].x; acc.y += g3.x*w[12].y; acc.z += g3.x*w[12].z; acc.w += g3.x*w[12].w;
        acc.x += g3.y*w[13].x; acc.y += g3.y*w[13].y; acc.z += g3.y*w[13].z; acc.w += g3.y*w[13].w;
        acc.x += g3.z*w[14].x; acc.y += g3.z*w[14].y; acc.z += g3.z*w[14].z; acc.w += g3.z*w[14].w;
        acc.x += g3.w*w[15].x; acc.y += g3.w*w[15].y; acc.z += g3.w*w[15].z; acc.w += g3.w*w[15].w;
        *reinterpret_cast<float4*>(&out[(size_t)row * N_NODES + col0]) = acc;
    }
}

extern "C" void kernel_launch(void* const* d_in, const int* in_sizes, int n_in,
                              void* d_out, int out_size, void* d_ws, size_t ws_size,
                              hipStream_t stream) {
    const float* x  = (const float*)d_in[0];
    const float* W1 = (const float*)d_in[1];
    const float* b1 = (const float*)d_in[2];
    const float* W2 = (const float*)d_in[3];
    const float* b2 = (const float*)d_in[4];
    const float* W3 = (const float*)d_in[5];
    const float* b3 = (const float*)d_in[6];
    // d_in[7] = edge_index: fixed directed chain i->i+1 (structure hardcoded)

    float* g   = (float*)d_ws;     // [N_NODES, H2] = 512 KB
    float* out = (float*)d_out;

    gnn_front<<<N_NODES / FRONT_ROWS, 256, 0, stream>>>(x, W1, b1, W2, b2, g);

    gnn_out<<<2048, 256, 0, stream>>>(g, W3, b3, out);
}

// Round 12
// 61.850 us; speedup vs baseline: 2.0247x; 2.0247x over previous
//
#include <hip/hip_runtime.h>

// GCN on a directed chain i->i+1 with self-loops.
//
// Math (symmetric normalization on chain + self-loops):
//   deg[0]=1, deg[j>=1]=2  ->  dis[0]=1, dis[j>=1]=1/sqrt(2)
//   stencil(h)[j] = a_j*h[j] + c_j*h[j-1],  a_0=1, a_j=0.5 (j>=1)
//   c_0=0 (and c_j=0 for j<0), c_1=1/sqrt(2), c_j=0.5 (j>=2)
//   out = g @ W3 + b3   where  g = stencil(relu(stencil(relu(stencil(x@W1)
//         +b1)@W2)+b2))  (stencil commutes with right-matmul by linearity).
//
// Evidence ledger for K2 (268 MB store stream, fill-demonstrated ~7.1 TB/s):
//   R7  blocks 2048->512:            69.4us (-24%; needs >=8 blocks/CU)
//   R8  nontemporal stores:          64.6us (L2 write-back HELPS; reverted)
//   R9  4-row store bursting:        55.1us (neutral)
//   R10 float2 width + 2x occupancy: 56.6us (neutral)
//   R11 fill-mimic sweep, gtid-derived rows: 125.2us — CONFOUNDED: rbase
//       from gtid killed the scalar g-broadcast (vector loads on the
//       critical path). Mapping hypothesis not actually tested.
// R11 -> R12: same sweep mapping, R6 codegen preserved. rbase=blockIdx>>3
// (SGPR) -> g loads stay s_load broadcasts. At iteration i, ALL blocks
// jointly write rows i*256..i*256+255 = one contiguous 8MB window sweeping
// monotonically (fill-like DRAM row locality), vs R6's 268MB instantaneous
// scatter. Inner loop byte-identical to R6; only the row->time mapping moved.

#define N_NODES 8192
#define F_IN 4
#define H1 32
#define H2 16

#define FRONT_ROWS 128        // g-rows per front block

__device__ __forceinline__ float coefA(int j) { return j == 0 ? 1.0f : 0.5f; }
__device__ __forceinline__ float coefC(int j) {
    return j <= 0 ? 0.0f : (j == 1 ? 0.70710678118654752f : 0.5f);
}

// ---------------- K1: x -> g = stencil(h2), [N,16] ----------------
__global__ void __launch_bounds__(256) gnn_front(
    const float* __restrict__ x,  const float* __restrict__ W1,
    const float* __restrict__ b1, const float* __restrict__ W2,
    const float* __restrict__ b2, float* __restrict__ g)
{
    __shared__ float sW1t[H1 * F_IN];            // transposed: [k][f]
    __shared__ float sb1[H1];
    __shared__ float sW2[H1 * H2];               // [k][m]
    __shared__ float sb2[H2];
    __shared__ float st2[FRONT_ROWS + 2][H2];    // 8320 B

    const int t = threadIdx.x;
    const int row0 = blockIdx.x * FRONT_ROWS;

    if (t < H1 * F_IN) sW1t[t] = W1[(t & 3) * H1 + (t >> 2)];  // sW1t[k*4+f]=W1[f][k]
    if (t < H1) sb1[t] = b1[t];
    if (t < H2) sb2[t] = b2[t];
    sW2[t] = W2[t];
    sW2[t + 256] = W2[t + 256];
    __syncthreads();

    // t2 rows for nodes row0-2 .. row0+FRONT_ROWS-1, lanes 0..FRONT_ROWS+1
    if (t < FRONT_ROWS + 2) {
        const int jj = row0 - 2 + t;
        float acc[H2];
        #pragma unroll
        for (int m = 0; m < H2; ++m) acc[m] = 0.f;
        if (jj >= 0) {
            const float4 xc = *reinterpret_cast<const float4*>(&x[jj * F_IN]);
            float4 xp = make_float4(0.f, 0.f, 0.f, 0.f);
            if (jj >= 1) xp = *reinterpret_cast<const float4*>(&x[(jj - 1) * F_IN]);
            const float a = coefA(jj), c = coefC(jj);
            #pragma unroll
            for (int k = 0; k < H1; ++k) {
                const float4 wk = *reinterpret_cast<const float4*>(&sW1t[k * 4]);
                const float t1c = xc.x * wk.x + xc.y * wk.y + xc.z * wk.z + xc.w * wk.w;
                const float t1p = xp.x * wk.x + xp.y * wk.y + xp.z * wk.z + xp.w * wk.w;
                float h = a * t1c + c * t1p + sb1[k];
                h = h > 0.f ? h : 0.f;
                #pragma unroll
                for (int m = 0; m < H2; ++m) acc[m] += h * sW2[k * H2 + m];
            }
        }
        #pragma unroll
        for (int m = 0; m < H2; ++m) st2[t][m] = acc[m];
    }
    __syncthreads();

    // g rows for nodes row0 .. row0+FRONT_ROWS-1, lanes 0..FRONT_ROWS-1
    if (t < FRONT_ROWS) {
        const int j = row0 + t;   // st2[t+2]=t2[j], st2[t+1]=t2[j-1], st2[t]=t2[j-2]
        const float aj = coefA(j),     cj = coefC(j);
        const float ap = coefA(j - 1), cp = coefC(j - 1);
        float gout[H2];
        #pragma unroll
        for (int m = 0; m < H2; ++m) {
            const float bm = sb2[m];
            float h2c = aj * st2[t + 2][m] + cj * st2[t + 1][m] + bm;
            h2c = h2c > 0.f ? h2c : 0.f;
            float h2p = ap * st2[t + 1][m] + cp * st2[t][m] + bm;
            h2p = h2p > 0.f ? h2p : 0.f;
            gout[m] = aj * h2c + cj * h2p;       // g[j] = stencil(h2)[j]
        }
        #pragma unroll
        for (int m = 0; m < H2; m += 4) {
            *reinterpret_cast<float4*>(&g[j * H2 + m]) =
                make_float4(gout[m], gout[m + 1], gout[m + 2], gout[m + 3]);
        }
    }
}

// ------- K2: out = g @ W3 + b3, [N, N] — sweeping-window streamer -------
// Block b: col-chunk = (b&7)*1024, row-phase = b>>3. Iteration i writes
// row (b>>3) + i*256. All 2048 blocks at iteration i cover rows
// i*256..i*256+255 -> one contiguous 8MB window sweeping 0->268MB.
// rbase is blockIdx-derived (SGPR) -> g loads remain scalar broadcasts.
__global__ void __launch_bounds__(256) gnn_out(
    const float* __restrict__ g, const float* __restrict__ W3,
    const float* __restrict__ b3, float* __restrict__ out)
{
    const int t = threadIdx.x;
    const int col0  = (blockIdx.x & 7) * 1024 + t * 4;
    const int rbase = blockIdx.x >> 3;                  // 0..255

    // W3 column slab in registers: 16 x float4 = 64 VGPRs, loaded once
    float4 w[H2];
    #pragma unroll
    for (int k = 0; k < H2; ++k)
        w[k] = *reinterpret_cast<const float4*>(&W3[k * N_NODES + col0]);
    const float4 bb = *reinterpret_cast<const float4*>(&b3[col0]);

    const float* gr = g + rbase * H2;
    float* po = out + (size_t)rbase * N_NODES + col0;

    #pragma unroll 4
    for (int i = 0; i < N_NODES / 256; ++i) {           // 32 iterations
        // wave-uniform addresses -> scalar-cache broadcast loads
        const float4 g0 = *reinterpret_cast<const float4*>(&gr[0]);
        const float4 g1 = *reinterpret_cast<const float4*>(&gr[4]);
        const float4 g2 = *reinterpret_cast<const float4*>(&gr[8]);
        const float4 g3 = *reinterpret_cast<const float4*>(&gr[12]);
        float4 acc = bb;
        acc.x += g0.x*w[0].x;  acc.y += g0.x*w[0].y;  acc.z += g0.x*w[0].z;  acc.w += g0.x*w[0].w;
        acc.x += g0.y*w[1].x;  acc.y += g0.y*w[1].y;  acc.z += g0.y*w[1].z;  acc.w += g0.y*w[1].w;
        acc.x += g0.z*w[2].x;  acc.y += g0.z*w[2].y;  acc.z += g0.z*w[2].z;  acc.w += g0.z*w[2].w;
        acc.x += g0.w*w[3].x;  acc.y += g0.w*w[3].y;  acc.z += g0.w*w[3].z;  acc.w += g0.w*w[3].w;
        acc.x += g1.x*w[4].x;  acc.y += g1.x*w[4].y;  acc.z += g1.x*w[4].z;  acc.w += g1.x*w[4].w;
        acc.x += g1.y*w[5].x;  acc.y += g1.y*w[5].y;  acc.z += g1.y*w[5].z;  acc.w += g1.y*w[5].w;
        acc.x += g1.z*w[6].x;  acc.y += g1.z*w[6].y;  acc.z += g1.z*w[6].z;  acc.w += g1.z*w[6].w;
        acc.x += g1.w*w[7].x;  acc.y += g1.w*w[7].y;  acc.z += g1.w*w[7].z;  acc.w += g1.w*w[7].w;
        acc.x += g2.x*w[8].x;  acc.y += g2.x*w[8].y;  acc.z += g2.x*w[8].z;  acc.w += g2.x*w[8].w;
        acc.x += g2.y*w[9].x;  acc.y += g2.y*w[9].y;  acc.z += g2.y*w[9].z;  acc.w += g2.y*w[9].w;
        acc.x += g2.z*w[10].x; acc.y += g2.z*w[10].y; acc.z += g2.z*w[10].z; acc.w += g2.z*w[10].w;
        acc.x += g2.w*w[11].x; acc.y += g2.w*w[11].y; acc.z += g2.w*w[11].z; acc.w += g2.w*w[11].w;
        acc.x += g3.x*w[12].x; acc.y += g3.x*w[12].y; acc.z += g3.x*w[12].z; acc.w += g3.x*w[12].w;
        acc.x += g3.y*w[13].x; acc.y += g3.y*w[13].y; acc.z += g3.y*w[13].z; acc.w += g3.y*w[13].w;
        acc.x += g3.z*w[14].x; acc.y += g3.z*w[14].y; acc.z += g3.z*w[14].z; acc.w += g3.z*w[14].w;
        acc.x += g3.w*w[15].x; acc.y += g3.w*w[15].y; acc.z += g3.w*w[15].z; acc.w += g3.w*w[15].w;
        *reinterpret_cast<float4*>(po) = acc;
        gr += 256 * H2;                                  // next row-phase
        po += (size_t)256 * N_NODES;                     // +8MB window step
    }
}

extern "C" void kernel_launch(void* const* d_in, const int* in_sizes, int n_in,
                              void* d_out, int out_size, void* d_ws, size_t ws_size,
                              hipStream_t stream) {
    const float* x  = (const float*)d_in[0];
    const float* W1 = (const float*)d_in[1];
    const float* b1 = (const float*)d_in[2];
    const float* W2 = (const float*)d_in[3];
    const float* b2 = (const float*)d_in[4];
    const float* W3 = (const float*)d_in[5];
    const float* b3 = (const float*)d_in[6];
    // d_in[7] = edge_index: fixed directed chain i->i+1 (structure hardcoded)

    float* g   = (float*)d_ws;     // [N_NODES, H2] = 512 KB
    float* out = (float*)d_out;

    gnn_front<<<N_NODES / FRONT_ROWS, 256, 0, stream>>>(x, W1, b1, W2, b2, g);

    gnn_out<<<2048, 256, 0, stream>>>(g, W3, b3, out);
}

// Round 13
// 55.847 us; speedup vs baseline: 2.2424x; 1.1075x over previous
//
#include <hip/hip_runtime.h>

// GCN on a directed chain i->i+1 with self-loops.
//
// Math (symmetric normalization on chain + self-loops):
//   deg[0]=1, deg[j>=1]=2  ->  dis[0]=1, dis[j>=1]=1/sqrt(2)
//   stencil(h)[j] = a_j*h[j] + c_j*h[j-1],  a_0=1, a_j=0.5 (j>=1)
//   c_0=0 (and c_j=0 for j<0), c_1=1/sqrt(2), c_j=0.5 (j>=2)
//   out = g @ W3 + b3   where  g = stencil(relu(stencil(relu(stencil(x@W1)
//         +b1)@W2)+b2))  (stencil commutes with right-matmul by linearity).
//
// Evidence ledger for K2 (268 MB store stream, fill-demonstrated ~7.1 TB/s):
//   R7  blocks 2048->512:            69.4us (-24%; needs >=8 blocks/CU)
//   R8  nontemporal stores:          64.6us (L2 write-back HELPS; reverted)
//   R9  4-row store bursting:        55.1us (neutral)
//   R10 float2 width + 2x occupancy: 56.6us (neutral; lockstep waves)
//   R11 gtid-derived rows:           125us  (confounded: killed s_load bcast)
//   R12 fill-pattern sweep, clean:   61.9us (mapping axis FALSIFIED — gap
//                                            is the load->FMA->store dep)
// R12 -> R13 (single variable vs R6-best 54.4us): 2-deep software pipeline
// on the g-row scalar loads. Waves in a block run lockstep -> all hit the
// s_waitcnt(g-row) together and the SIMD drains; prefetching row r+1's
// s_load before row r's 64-FMA block gives ~128+ cycles of in-wave cover.
// Static A/B register names (rule #20), addresses pure blockIdx-derived
// (SGPR) so scalar-broadcast codegen survives (R11 lesson).

#define N_NODES 8192
#define F_IN 4
#define H1 32
#define H2 16

#define FRONT_ROWS 128        // g-rows per front block
#define COLS_PER_BLOCK 1024   // 256 threads * float4
#define ROWS_PER_BLOCK 32     // 2048 blocks = 8 blocks/CU (R6 known-best)

__device__ __forceinline__ float coefA(int j) { return j == 0 ? 1.0f : 0.5f; }
__device__ __forceinline__ float coefC(int j) {
    return j <= 0 ? 0.0f : (j == 1 ? 0.70710678118654752f : 0.5f);
}

// ---------------- K1: x -> g = stencil(h2), [N,16] ----------------
__global__ void __launch_bounds__(256) gnn_front(
    const float* __restrict__ x,  const float* __restrict__ W1,
    const float* __restrict__ b1, const float* __restrict__ W2,
    const float* __restrict__ b2, float* __restrict__ g)
{
    __shared__ float sW1t[H1 * F_IN];            // transposed: [k][f]
    __shared__ float sb1[H1];
    __shared__ float sW2[H1 * H2];               // [k][m]
    __shared__ float sb2[H2];
    __shared__ float st2[FRONT_ROWS + 2][H2];    // 8320 B

    const int t = threadIdx.x;
    const int row0 = blockIdx.x * FRONT_ROWS;

    if (t < H1 * F_IN) sW1t[t] = W1[(t & 3) * H1 + (t >> 2)];  // sW1t[k*4+f]=W1[f][k]
    if (t < H1) sb1[t] = b1[t];
    if (t < H2) sb2[t] = b2[t];
    sW2[t] = W2[t];
    sW2[t + 256] = W2[t + 256];
    __syncthreads();

    // t2 rows for nodes row0-2 .. row0+FRONT_ROWS-1, lanes 0..FRONT_ROWS+1
    if (t < FRONT_ROWS + 2) {
        const int jj = row0 - 2 + t;
        float acc[H2];
        #pragma unroll
        for (int m = 0; m < H2; ++m) acc[m] = 0.f;
        if (jj >= 0) {
            const float4 xc = *reinterpret_cast<const float4*>(&x[jj * F_IN]);
            float4 xp = make_float4(0.f, 0.f, 0.f, 0.f);
            if (jj >= 1) xp = *reinterpret_cast<const float4*>(&x[(jj - 1) * F_IN]);
            const float a = coefA(jj), c = coefC(jj);
            #pragma unroll
            for (int k = 0; k < H1; ++k) {
                const float4 wk = *reinterpret_cast<const float4*>(&sW1t[k * 4]);
                const float t1c = xc.x * wk.x + xc.y * wk.y + xc.z * wk.z + xc.w * wk.w;
                const float t1p = xp.x * wk.x + xp.y * wk.y + xp.z * wk.z + xp.w * wk.w;
                float h = a * t1c + c * t1p + sb1[k];
                h = h > 0.f ? h : 0.f;
                #pragma unroll
                for (int m = 0; m < H2; ++m) acc[m] += h * sW2[k * H2 + m];
            }
        }
        #pragma unroll
        for (int m = 0; m < H2; ++m) st2[t][m] = acc[m];
    }
    __syncthreads();

    // g rows for nodes row0 .. row0+FRONT_ROWS-1, lanes 0..FRONT_ROWS-1
    if (t < FRONT_ROWS) {
        const int j = row0 + t;   // st2[t+2]=t2[j], st2[t+1]=t2[j-1], st2[t]=t2[j-2]
        const float aj = coefA(j),     cj = coefC(j);
        const float ap = coefA(j - 1), cp = coefC(j - 1);
        float gout[H2];
        #pragma unroll
        for (int m = 0; m < H2; ++m) {
            const float bm = sb2[m];
            float h2c = aj * st2[t + 2][m] + cj * st2[t + 1][m] + bm;
            h2c = h2c > 0.f ? h2c : 0.f;
            float h2p = ap * st2[t + 1][m] + cp * st2[t][m] + bm;
            h2p = h2p > 0.f ? h2p : 0.f;
            gout[m] = aj * h2c + cj * h2p;       // g[j] = stencil(h2)[j]
        }
        #pragma unroll
        for (int m = 0; m < H2; m += 4) {
            *reinterpret_cast<float4*>(&g[j * H2 + m]) =
                make_float4(gout[m], gout[m + 1], gout[m + 2], gout[m + 3]);
        }
    }
}

// ------- K2: out = g @ W3 + b3, [N, N] — pipelined streamer -------
__global__ void __launch_bounds__(256) gnn_out(
    const float* __restrict__ g, const float* __restrict__ W3,
    const float* __restrict__ b3, float* __restrict__ out)
{
    const int t = threadIdx.x;
    const int col0 = blockIdx.x * COLS_PER_BLOCK + t * 4;
    const int row0 = blockIdx.y * ROWS_PER_BLOCK;

    // W3 column slab in registers: 16 x float4 = 64 VGPRs, loaded once
    float4 w[H2];
    #pragma unroll
    for (int k = 0; k < H2; ++k)
        w[k] = *reinterpret_cast<const float4*>(&W3[k * N_NODES + col0]);
    const float4 bb = *reinterpret_cast<const float4*>(&b3[col0]);

    auto ld4 = [](const float* p) { return *reinterpret_cast<const float4*>(p); };
    auto fma16 = [&](float4 g0, float4 g1, float4 g2, float4 g3) -> float4 {
        float4 a = bb;
        a.x += g0.x*w[0].x;  a.y += g0.x*w[0].y;  a.z += g0.x*w[0].z;  a.w += g0.x*w[0].w;
        a.x += g0.y*w[1].x;  a.y += g0.y*w[1].y;  a.z += g0.y*w[1].z;  a.w += g0.y*w[1].w;
        a.x += g0.z*w[2].x;  a.y += g0.z*w[2].y;  a.z += g0.z*w[2].z;  a.w += g0.z*w[2].w;
        a.x += g0.w*w[3].x;  a.y += g0.w*w[3].y;  a.z += g0.w*w[3].z;  a.w += g0.w*w[3].w;
        a.x += g1.x*w[4].x;  a.y += g1.x*w[4].y;  a.z += g1.x*w[4].z;  a.w += g1.x*w[4].w;
        a.x += g1.y*w[5].x;  a.y += g1.y*w[5].y;  a.z += g1.y*w[5].z;  a.w += g1.y*w[5].w;
        a.x += g1.z*w[6].x;  a.y += g1.z*w[6].y;  a.z += g1.z*w[6].z;  a.w += g1.z*w[6].w;
        a.x += g1.w*w[7].x;  a.y += g1.w*w[7].y;  a.z += g1.w*w[7].z;  a.w += g1.w*w[7].w;
        a.x += g2.x*w[8].x;  a.y += g2.x*w[8].y;  a.z += g2.x*w[8].z;  a.w += g2.x*w[8].w;
        a.x += g2.y*w[9].x;  a.y += g2.y*w[9].y;  a.z += g2.y*w[9].z;  a.w += g2.y*w[9].w;
        a.x += g2.z*w[10].x; a.y += g2.z*w[10].y; a.z += g2.z*w[10].z; a.w += g2.z*w[10].w;
        a.x += g2.w*w[11].x; a.y += g2.w*w[11].y; a.z += g2.w*w[11].z; a.w += g2.w*w[11].w;
        a.x += g3.x*w[12].x; a.y += g3.x*w[12].y; a.z += g3.x*w[12].z; a.w += g3.x*w[12].w;
        a.x += g3.y*w[13].x; a.y += g3.y*w[13].y; a.z += g3.y*w[13].z; a.w += g3.y*w[13].w;
        a.x += g3.z*w[14].x; a.y += g3.z*w[14].y; a.z += g3.z*w[14].z; a.w += g3.z*w[14].w;
        a.x += g3.w*w[15].x; a.y += g3.w*w[15].y; a.z += g3.w*w[15].z; a.w += g3.w*w[15].w;
        return a;
    };

    const float* gr = g + row0 * H2;          // pure SGPR-derived (blockIdx)
    float* po = out + (size_t)row0 * N_NODES + col0;

    // ---- 2-deep software pipeline over the 32 rows ----
    // prologue: row 0 into A
    float4 A0 = ld4(gr + 0), A1 = ld4(gr + 4), A2 = ld4(gr + 8), A3 = ld4(gr + 12);
    const float* pnext = gr + H2;             // row 1

    for (int it = 0; it < ROWS_PER_BLOCK / 2; ++it) {
        // prefetch row 2it+1 into B (issues before A's FMA block)
        float4 B0 = ld4(pnext + 0), B1 = ld4(pnext + 4),
               B2 = ld4(pnext + 8), B3 = ld4(pnext + 12);
        *reinterpret_cast<float4*>(po) = fma16(A0, A1, A2, A3);

        // prefetch row 2it+2 into A (clamped on last iteration; dead value)
        const float* pnn = (it < ROWS_PER_BLOCK / 2 - 1) ? (pnext + H2) : pnext;
        A0 = ld4(pnn + 0); A1 = ld4(pnn + 4); A2 = ld4(pnn + 8); A3 = ld4(pnn + 12);
        *reinterpret_cast<float4*>(po + N_NODES) = fma16(B0, B1, B2, B3);

        pnext += 2 * H2;
        po += 2 * N_NODES;
    }
}

extern "C" void kernel_launch(void* const* d_in, const int* in_sizes, int n_in,
                              void* d_out, int out_size, void* d_ws, size_t ws_size,
                              hipStream_t stream) {
    const float* x  = (const float*)d_in[0];
    const float* W1 = (const float*)d_in[1];
    const float* b1 = (const float*)d_in[2];
    const float* W2 = (const float*)d_in[3];
    const float* b2 = (const float*)d_in[4];
    const float* W3 = (const float*)d_in[5];
    const float* b3 = (const float*)d_in[6];
    // d_in[7] = edge_index: fixed directed chain i->i+1 (structure hardcoded)

    float* g   = (float*)d_ws;     // [N_NODES, H2] = 512 KB
    float* out = (float*)d_out;

    gnn_front<<<N_NODES / FRONT_ROWS, 256, 0, stream>>>(x, W1, b1, W2, b2, g);

    dim3 grid(N_NODES / COLS_PER_BLOCK, N_NODES / ROWS_PER_BLOCK);  // 8 x 256
    gnn_out<<<grid, 256, 0, stream>>>(g, W3, b3, out);
}

// Round 14
// 53.440 us; speedup vs baseline: 2.3434x; 1.0450x over previous
//
#include <hip/hip_runtime.h>

// GCN on a directed chain i->i+1 with self-loops.
//
// Math (symmetric normalization on chain + self-loops):
//   deg[0]=1, deg[j>=1]=2  ->  dis[0]=1, dis[j>=1]=1/sqrt(2)
//   stencil(h)[j] = a_j*h[j] + c_j*h[j-1],  a_0=1, a_j=0.5 (j>=1)
//   c_0=0 (and c_j=0 for j<0), c_1=1/sqrt(2), c_j=0.5 (j>=2)
//   out = g @ W3 + b3   where  g = stencil(relu(stencil(relu(stencil(x@W1)
//         +b1)@W2)+b2))  (stencil commutes with right-matmul by linearity).
//
// Evidence ledger for K2 (268 MB store stream, fill-demonstrated ~7.1 TB/s):
//   R7  blocks 2048->512:            69.4us (-24%; needs >=8 blocks/CU)
//   R8  nontemporal stores:          64.6us (L2 write-back HELPS; reverted)
//   R9  4-row store bursting:        55.1us (neutral)
//   R10 float2 width + 2x occupancy: 56.6us (neutral)
//   R11 gtid-derived rows:           125us  (confounded: killed s_load bcast)
//   R12 fill-pattern sweep, clean:   61.9us (mapping axis falsified)
//   R13 2-deep g-row pipeline:       55.8us (neutral; latency axis falsified)
// K2 is pinned at ~5.4 TB/s across every configuration -> structural limit
// of a dependent compute+store stream vs the dependency-free 1GB fill.
// R13 -> R14: revert K2 to R6-exact (known best). Single variable: K1
// restructured from 64 big blocks on 64 CUs (<=130/256 lanes active) to
// 256 one-wave blocks (FRONT_ROWS=32, 64 thr) - every CU gets a block,
// ~4x less work per block. Targets the ~3us front+launch slice.

#define N_NODES 8192
#define F_IN 4
#define H1 32
#define H2 16

#define FRONT_ROWS 32         // g-rows per front block (one-wave blocks)
#define COLS_PER_BLOCK 1024   // 256 threads * float4
#define ROWS_PER_BLOCK 32     // 2048 blocks = 8 blocks/CU (R6 known-best)

__device__ __forceinline__ float coefA(int j) { return j == 0 ? 1.0f : 0.5f; }
__device__ __forceinline__ float coefC(int j) {
    return j <= 0 ? 0.0f : (j == 1 ? 0.70710678118654752f : 0.5f);
}

// ---------------- K1: x -> g = stencil(h2), [N,16] ----------------
// 256 blocks x 64 threads (one wave each): one block per CU.
__global__ void __launch_bounds__(64) gnn_front(
    const float* __restrict__ x,  const float* __restrict__ W1,
    const float* __restrict__ b1, const float* __restrict__ W2,
    const float* __restrict__ b2, float* __restrict__ g)
{
    __shared__ float sW1t[H1 * F_IN];            // transposed: [k][f]
    __shared__ float sb1[H1];
    __shared__ float sW2[H1 * H2];               // [k][m]
    __shared__ float sb2[H2];
    __shared__ float st2[FRONT_ROWS + 2][H2];    // 34 x 16

    const int t = threadIdx.x;                   // 0..63
    const int row0 = blockIdx.x * FRONT_ROWS;

    // Stage small weights to LDS (64-thread staging).
    #pragma unroll
    for (int i = 0; i < 2; ++i) {
        const int idx = i * 64 + t;                  // 0..127
        sW1t[idx] = W1[(idx & 3) * H1 + (idx >> 2)]; // sW1t[k*4+f] = W1[f][k]
    }
    if (t < H1) sb1[t] = b1[t];
    if (t < H2) sb2[t] = b2[t];
    #pragma unroll
    for (int i = 0; i < 8; ++i) sW2[i * 64 + t] = W2[i * 64 + t];
    __syncthreads();

    // t2 rows for nodes row0-2 .. row0+FRONT_ROWS-1, lanes 0..FRONT_ROWS+1
    if (t < FRONT_ROWS + 2) {
        const int jj = row0 - 2 + t;
        float acc[H2];
        #pragma unroll
        for (int m = 0; m < H2; ++m) acc[m] = 0.f;
        if (jj >= 0) {
            const float4 xc = *reinterpret_cast<const float4*>(&x[jj * F_IN]);
            float4 xp = make_float4(0.f, 0.f, 0.f, 0.f);
            if (jj >= 1) xp = *reinterpret_cast<const float4*>(&x[(jj - 1) * F_IN]);
            const float a = coefA(jj), c = coefC(jj);
            #pragma unroll
            for (int k = 0; k < H1; ++k) {
                const float4 wk = *reinterpret_cast<const float4*>(&sW1t[k * 4]);
                const float t1c = xc.x * wk.x + xc.y * wk.y + xc.z * wk.z + xc.w * wk.w;
                const float t1p = xp.x * wk.x + xp.y * wk.y + xp.z * wk.z + xp.w * wk.w;
                float h = a * t1c + c * t1p + sb1[k];
                h = h > 0.f ? h : 0.f;
                #pragma unroll
                for (int m = 0; m < H2; ++m) acc[m] += h * sW2[k * H2 + m];
            }
        }
        #pragma unroll
        for (int m = 0; m < H2; ++m) st2[t][m] = acc[m];
    }
    __syncthreads();

    // g rows for nodes row0 .. row0+FRONT_ROWS-1, lanes 0..FRONT_ROWS-1
    if (t < FRONT_ROWS) {
        const int j = row0 + t;   // st2[t+2]=t2[j], st2[t+1]=t2[j-1], st2[t]=t2[j-2]
        const float aj = coefA(j),     cj = coefC(j);
        const float ap = coefA(j - 1), cp = coefC(j - 1);
        float gout[H2];
        #pragma unroll
        for (int m = 0; m < H2; ++m) {
            const float bm = sb2[m];
            float h2c = aj * st2[t + 2][m] + cj * st2[t + 1][m] + bm;
            h2c = h2c > 0.f ? h2c : 0.f;
            float h2p = ap * st2[t + 1][m] + cp * st2[t][m] + bm;
            h2p = h2p > 0.f ? h2p : 0.f;
            gout[m] = aj * h2c + cj * h2p;       // g[j] = stencil(h2)[j]
        }
        #pragma unroll
        for (int m = 0; m < H2; m += 4) {
            *reinterpret_cast<float4*>(&g[j * H2 + m]) =
                make_float4(gout[m], gout[m + 1], gout[m + 2], gout[m + 3]);
        }
    }
}

// ---------------- K2: out = g @ W3 + b3, [N, N] — R6-exact streamer ----------------
__global__ void __launch_bounds__(256) gnn_out(
    const float* __restrict__ g, const float* __restrict__ W3,
    const float* __restrict__ b3, float* __restrict__ out)
{
    const int t = threadIdx.x;
    const int col0 = blockIdx.x * COLS_PER_BLOCK + t * 4;
    const int row0 = blockIdx.y * ROWS_PER_BLOCK;

    // W3 column slab in registers: 16 x float4 = 64 VGPRs, loaded once
    float4 w[H2];
    #pragma unroll
    for (int k = 0; k < H2; ++k)
        w[k] = *reinterpret_cast<const float4*>(&W3[k * N_NODES + col0]);
    const float4 bb = *reinterpret_cast<const float4*>(&b3[col0]);

    const float* gr = g + row0 * H2;
    float* po = out + (size_t)row0 * N_NODES + col0;

    #pragma unroll 4
    for (int r = 0; r < ROWS_PER_BLOCK; ++r) {
        // wave-uniform addresses -> scalar-cache broadcast loads
        const float4 g0 = *reinterpret_cast<const float4*>(&gr[r * H2 + 0]);
        const float4 g1 = *reinterpret_cast<const float4*>(&gr[r * H2 + 4]);
        const float4 g2 = *reinterpret_cast<const float4*>(&gr[r * H2 + 8]);
        const float4 g3 = *reinterpret_cast<const float4*>(&gr[r * H2 + 12]);
        float4 acc = bb;
        acc.x += g0.x*w[0].x;  acc.y += g0.x*w[0].y;  acc.z += g0.x*w[0].z;  acc.w += g0.x*w[0].w;
        acc.x += g0.y*w[1].x;  acc.y += g0.y*w[1].y;  acc.z += g0.y*w[1].z;  acc.w += g0.y*w[1].w;
        acc.x += g0.z*w[2].x;  acc.y += g0.z*w[2].y;  acc.z += g0.z*w[2].z;  acc.w += g0.z*w[2].w;
        acc.x += g0.w*w[3].x;  acc.y += g0.w*w[3].y;  acc.z += g0.w*w[3].z;  acc.w += g0.w*w[3].w;
        acc.x += g1.x*w[4].x;  acc.y += g1.x*w[4].y;  acc.z += g1.x*w[4].z;  acc.w += g1.x*w[4].w;
        acc.x += g1.y*w[5].x;  acc.y += g1.y*w[5].y;  acc.z += g1.y*w[5].z;  acc.w += g1.y*w[5].w;
        acc.x += g1.z*w[6].x;  acc.y += g1.z*w[6].y;  acc.z += g1.z*w[6].z;  acc.w += g1.z*w[6].w;
        acc.x += g1.w*w[7].x;  acc.y += g1.w*w[7].y;  acc.z += g1.w*w[7].z;  acc.w += g1.w*w[7].w;
        acc.x += g2.x*w[8].x;  acc.y += g2.x*w[8].y;  acc.z += g2.x*w[8].z;  acc.w += g2.x*w[8].w;
        acc.x += g2.y*w[9].x;  acc.y += g2.y*w[9].y;  acc.z += g2.y*w[9].z;  acc.w += g2.y*w[9].w;
        acc.x += g2.z*w[10].x; acc.y += g2.z*w[10].y; acc.z += g2.z*w[10].z; acc.w += g2.z*w[10].w;
        acc.x += g2.w*w[11].x; acc.y += g2.w*w[11].y; acc.z += g2.w*w[11].z; acc.w += g2.w*w[11].w;
        acc.x += g3.x*w[12].x; acc.y += g3.x*w[12].y; acc.z += g3.x*w[12].z; acc.w += g3.x*w[12].w;
        acc.x += g3.y*w[13].x; acc.y += g3.y*w[13].y; acc.z += g3.y*w[13].z; acc.w += g3.y*w[13].w;
        acc.x += g3.z*w[14].x; acc.y += g3.z*w[14].y; acc.z += g3.z*w[14].z; acc.w += g3.z*w[14].w;
        acc.x += g3.w*w[15].x; acc.y += g3.w*w[15].y; acc.z += g3.w*w[15].z; acc.w += g3.w*w[15].w;
        *reinterpret_cast<float4*>(po) = acc;
        po += N_NODES;
    }
}

extern "C" void kernel_launch(void* const* d_in, const int* in_sizes, int n_in,
                              void* d_out, int out_size, void* d_ws, size_t ws_size,
                              hipStream_t stream) {
    const float* x  = (const float*)d_in[0];
    const float* W1 = (const float*)d_in[1];
    const float* b1 = (const float*)d_in[2];
    const float* W2 = (const float*)d_in[3];
    const float* b2 = (const float*)d_in[4];
    const float* W3 = (const float*)d_in[5];
    const float* b3 = (const float*)d_in[6];
    // d_in[7] = edge_index: fixed directed chain i->i+1 (structure hardcoded)

    float* g   = (float*)d_ws;     // [N_NODES, H2] = 512 KB
    float* out = (float*)d_out;

    gnn_front<<<N_NODES / FRONT_ROWS, 64, 0, stream>>>(x, W1, b1, W2, b2, g);

    dim3 grid(N_NODES / COLS_PER_BLOCK, N_NODES / ROWS_PER_BLOCK);  // 8 x 256
    gnn_out<<<grid, 256, 0, stream>>>(g, W3, b3, out);
}